// Round 9
// baseline (1191.885 us; speedup 1.0000x reference)
//
#include <hip/hip_runtime.h>
#include <hip/hip_bf16.h>

#define B_   256
#define T_   512
#define H_   128
#define G3_  384

// ---- tiled GEMM config ----
#define TM   128
#define TN   128
#define TK   32
#define LDA  132

__device__ __forceinline__ float sigmoid_f(float x) {
    return 1.0f / (1.0f + __expf(-x));
}
__device__ __forceinline__ float tanh_f(float x) {
    return 1.0f - 2.0f / (__expf(2.0f * x) + 1.0f);
}

// Butterfly sum over each aligned 8-lane group, pure DPP (no LDS pipe),
// result valid on ALL lanes: quad_perm xor1, quad_perm xor2, row_half_mirror.
__device__ __forceinline__ float bfly_fold8(float v) {
    int x;
    x = __builtin_amdgcn_update_dpp(0, __float_as_int(v), 0x0B1, 0xF, 0xF, true);
    v += __int_as_float(x);   // xor 1
    x = __builtin_amdgcn_update_dpp(0, __float_as_int(v), 0x04E, 0xF, 0xF, true);
    v += __int_as_float(x);   // xor 2
    x = __builtin_amdgcn_update_dpp(0, __float_as_int(v), 0x141, 0xF, 0xF, true);
    v += __int_as_float(x);   // other quad (half mirror)
    return v;
}

#define DOT4(acc, hv, wv)                                        \
    acc = fmaf((hv).x, (wv).x, acc);                             \
    acc = fmaf((hv).y, (wv).y, acc);                             \
    acc = fmaf((hv).z, (wv).z, acc);                             \
    acc = fmaf((hv).w, (wv).w, acc);

// volatile 4-float load: cannot be rematerialized/sunk into the loop, so the
// register allocator must keep (or honestly spill) the values — defeats the
// load-sinking that kept VGPR_Count at 40 through R2-R8.
#define VLD4(dst, base, off) {                                   \
    const volatile float* _p = (base) + (off);                   \
    dst.x = _p[0]; dst.y = _p[1]; dst.z = _p[2]; dst.w = _p[3]; }

// ---------------------------------------------------------------------------
// gx GEMM (unchanged from R2 — ~150 us, healthy)
// ---------------------------------------------------------------------------
template<bool GATHER>
__global__ __launch_bounds__(256, 2)
void gx_gemm(const float* __restrict__ X,
             const int*   __restrict__ idx,
             const float* __restrict__ emb,
             const float* __restrict__ W,     // [384,128] row-major
             const float* __restrict__ bias,  // [384]
             float*       __restrict__ gx)    // [M,384]
{
    __shared__ __align__(16) float As[2][TK][LDA];
    __shared__ __align__(16) float Bs[2][TK][LDA];

    const int tid = threadIdx.x;
    const int tn  = tid & 15;
    const int tm  = tid >> 4;
    const int n0  = blockIdx.x * TN;
    const int m0  = blockIdx.y * TM;

    const int q  = tid & 7;
    const float* rowA[4];
    const float* rowB[4];
#pragma unroll
    for (int s = 0; s < 4; s++) {
        const int r = (tid >> 3) + 32 * s;
        rowA[s] = GATHER ? (emb + (size_t)idx[m0 + r] * H_)
                         : (X + (size_t)(m0 + r) * H_);
        rowB[s] = W + (size_t)(n0 + r) * H_;
    }

    float4 stA[4], stB[4];
    auto load_chunk = [&](int kc) {
#pragma unroll
        for (int s = 0; s < 4; s++) {
            stA[s] = *(const float4*)(rowA[s] + kc + q * 4);
            stB[s] = *(const float4*)(rowB[s] + kc + q * 4);
        }
    };
    auto store_chunk = [&](int buf) {
#pragma unroll
        for (int s = 0; s < 4; s++) {
            const int r = (tid >> 3) + 32 * s;
#pragma unroll
            for (int d = 0; d < 4; d++) {
                As[buf][q * 4 + d][r] = ((const float*)&stA[s])[d];
                Bs[buf][q * 4 + d][r] = ((const float*)&stB[s])[d];
            }
        }
    };

    float4 acc[2][2][4];
#pragma unroll
    for (int a = 0; a < 2; a++)
#pragma unroll
        for (int b = 0; b < 2; b++)
#pragma unroll
            for (int c = 0; c < 4; c++) acc[a][b][c] = make_float4(0.f, 0.f, 0.f, 0.f);

    load_chunk(0);
    store_chunk(0);
    __syncthreads();

    for (int c = 0; c < 4; c++) {
        if (c < 3) load_chunk((c + 1) * TK);
        const int buf = c & 1;
#pragma unroll 4
        for (int k = 0; k < TK; k++) {
            float4 a0 = *(const float4*)&As[buf][k][tm * 4];
            float4 a1 = *(const float4*)&As[buf][k][64 + tm * 4];
            float4 b0 = *(const float4*)&Bs[buf][k][tn * 4];
            float4 b1 = *(const float4*)&Bs[buf][k][64 + tn * 4];
            float4 av[2] = {a0, a1}, bv[2] = {b0, b1};
#pragma unroll
            for (int mg = 0; mg < 2; mg++)
#pragma unroll
                for (int mi = 0; mi < 4; mi++) {
                    const float am = ((const float*)&av[mg])[mi];
#pragma unroll
                    for (int ng = 0; ng < 2; ng++) {
                        acc[mg][ng][mi].x = fmaf(am, bv[ng].x, acc[mg][ng][mi].x);
                        acc[mg][ng][mi].y = fmaf(am, bv[ng].y, acc[mg][ng][mi].y);
                        acc[mg][ng][mi].z = fmaf(am, bv[ng].z, acc[mg][ng][mi].z);
                        acc[mg][ng][mi].w = fmaf(am, bv[ng].w, acc[mg][ng][mi].w);
                    }
                }
        }
        if (c < 3) {
            store_chunk(buf ^ 1);
            __syncthreads();
        }
    }

    const float4 bb0 = *(const float4*)(bias + n0 + tn * 4);
    const float4 bb1 = *(const float4*)(bias + n0 + 64 + tn * 4);
#pragma unroll
    for (int mg = 0; mg < 2; mg++)
#pragma unroll
        for (int mi = 0; mi < 4; mi++) {
            const int m = m0 + mg * 64 + tm * 4 + mi;
            float* dst = gx + (size_t)m * G3_ + n0;
            float4 v0 = acc[mg][0][mi];
            v0.x += bb0.x; v0.y += bb0.y; v0.z += bb0.z; v0.w += bb0.w;
            float4 v1 = acc[mg][1][mi];
            v1.x += bb1.x; v1.y += bb1.y; v1.z += bb1.z; v1.w += bb1.w;
            *(float4*)(dst + tn * 4) = v0;
            *(float4*)(dst + 64 + tn * 4) = v1;
        }
}

// ---------------------------------------------------------------------------
// GRU recurrence, split-K (R7 structure). One block (1024 thr) per batch row.
// Thread (jg = tid>>3, ks = tid&7): owns W_hh rows 3jg..3jg+2, cols
// ks*16..+15 = 48 floats.
//
// R9 changes:
//  * W loaded via VOLATILE pointers -> illegal to rematerialize, so the
//    allocator must keep the fragment resident (R2-R8: it sank the loads
//    back into the loop, 196 KB/CU/step L1/L2 reloads = 1850 cyc/step).
//  * amdgpu_waves_per_eu(4,4): 16-wave workgroup at 1 block/CU IS 4
//    waves/EU (grid = 256 = 1/CU), so this is tight & feasible; sets the
//    allocator budget to 512/4 = 128 VGPRs >= ~80 needed.
// ---------------------------------------------------------------------------
template<bool STORE_H, bool FINAL>
__global__
__attribute__((amdgpu_flat_work_group_size(1024, 1024), amdgpu_waves_per_eu(4, 4)))
void gru_rec(const float* __restrict__ gx,   // [B,T,384]
             const float* __restrict__ Whh,  // [384,128]
             const float* __restrict__ bhh,  // [384]
             float*       __restrict__ hseq, // [B,T,128] if STORE_H
             const float* __restrict__ fc_w, // [3,128]  if FINAL
             const float* __restrict__ fc_b, // [3]      if FINAL
             float*       __restrict__ out)  // [B,3]    if FINAL
{
    __shared__ __align__(16) float h2[H_];   // swizzled h
    __shared__ float gh[G3_];

    const int tid = threadIdx.x;
    const int b   = blockIdx.x;
    const int jg  = tid >> 3;      // 0..127
    const int ks  = tid & 7;       // 0..7
    const int j0  = jg * 3;

    // --- W_hh fragment: 12 float4, volatile-loaded (non-rematerializable) ---
    const float* w0f = Whh + (size_t)(j0    ) * H_ + ks * 16;
    const float* w1f = Whh + (size_t)(j0 + 1) * H_ + ks * 16;
    const float* w2f = Whh + (size_t)(j0 + 2) * H_ + ks * 16;
    float4 w00, w01, w02, w03, w10, w11, w12, w13, w20, w21, w22, w23;
    VLD4(w00, w0f, 0)  VLD4(w01, w0f, 4)  VLD4(w02, w0f, 8)  VLD4(w03, w0f, 12)
    VLD4(w10, w1f, 0)  VLD4(w11, w1f, 4)  VLD4(w12, w1f, 8)  VLD4(w13, w1f, 12)
    VLD4(w20, w2f, 0)  VLD4(w21, w2f, 4)  VLD4(w22, w2f, 8)  VLD4(w23, w2f, 12)

    // --- gate-thread state (tid < 128) ---
    const bool gate = (tid < H_);
    float bhr = 0.f, bhz = 0.f, bhn = 0.f;
    float gr = 0.f, gz = 0.f, gn = 0.f;
    float h_old = 0.f;
    int   hw = 0;
    const float* gxb = gx + (size_t)b * T_ * G3_;
    if (gate) {
        bhr = bhh[tid]; bhz = bhh[tid + H_]; bhn = bhh[tid + 2 * H_];
        gr = gxb[tid]; gz = gxb[tid + H_]; gn = gxb[tid + 2 * H_];
        hw = ((tid >> 2) & 3) * 32 + (tid >> 4) * 4 + (tid & 3);
        h2[tid] = 0.0f;   // zeros are swizzle-invariant
    }
    __syncthreads();

    const int hb = ks * 4;  // base word of this thread's k-slice (swizzled)

    for (int t = 0; t < T_; t++) {
        // prefetch next step's gx (covered by this step's compute)
        float gr2 = 0.f, gz2 = 0.f, gn2 = 0.f;
        if (gate) {
            const float* gnx = gxb + (size_t)min(t + 1, T_ - 1) * G3_;
            gr2 = gnx[tid]; gz2 = gnx[tid + H_]; gn2 = gnx[tid + 2 * H_];
        }

        // ---- phase A: partial dots over this thread's k-slice ----
        float p0 = 0.f, p1 = 0.f, p2 = 0.f;
        {
            float4 hv;
            hv = *(const float4*)&h2[hb];
            DOT4(p0, hv, w00) DOT4(p1, hv, w10) DOT4(p2, hv, w20)
            hv = *(const float4*)&h2[32 + hb];
            DOT4(p0, hv, w01) DOT4(p1, hv, w11) DOT4(p2, hv, w21)
            hv = *(const float4*)&h2[64 + hb];
            DOT4(p0, hv, w02) DOT4(p1, hv, w12) DOT4(p2, hv, w22)
            hv = *(const float4*)&h2[96 + hb];
            DOT4(p0, hv, w03) DOT4(p1, hv, w13) DOT4(p2, hv, w23)
        }

        p0 = bfly_fold8(p0);
        p1 = bfly_fold8(p1);
        p2 = bfly_fold8(p2);
        if (ks == 0) {
            gh[j0] = p0; gh[j0 + 1] = p1; gh[j0 + 2] = p2;
        }
        __syncthreads();

        // ---- phase B: gates on threads 0..127 ----
        if (gate) {
            const float ghr = gh[tid] + bhr;
            const float ghz = gh[tid + H_] + bhz;
            const float ghn = gh[tid + 2 * H_] + bhn;
            const float r = sigmoid_f(gr + ghr);
            const float z = sigmoid_f(gz + ghz);
            const float n = tanh_f(gn + r * ghn);
            h_old = (1.0f - z) * n + z * h_old;
            h2[hw] = h_old;
            if (STORE_H) hseq[((size_t)b * T_ + t) * H_ + tid] = h_old;
            gr = gr2; gz = gz2; gn = gn2;
        }
        __syncthreads();
    }

    if (FINAL) {
        if (gate) gh[tid] = fmaxf(h_old, 0.0f);   // relu(last hidden)
        __syncthreads();
        if (tid < 3) {
            float acc = fc_b[tid];
            const float* fw = fc_w + tid * H_;
#pragma unroll
            for (int k = 0; k < H_; k++) acc = fmaf(gh[k], fw[k], acc);
            out[b * 3 + tid] = acc;
        }
    }
}

// ---------------------------------------------------------------------------
extern "C" void kernel_launch(void* const* d_in, const int* in_sizes, int n_in,
                              void* d_out, int out_size, void* d_ws, size_t ws_size,
                              hipStream_t stream)
{
    const int*   x    = (const int*)  d_in[0];
    const float* emb  = (const float*)d_in[1];
    const float* W_ih = (const float*)d_in[2];  // [2,384,128]
    const float* W_hh = (const float*)d_in[3];  // [2,384,128]
    const float* b_ih = (const float*)d_in[4];  // [2,384]
    const float* b_hh = (const float*)d_in[5];  // [2,384]
    const float* fc_w = (const float*)d_in[6];  // [3,128]
    const float* fc_b = (const float*)d_in[7];  // [3]
    float* out = (float*)d_out;

    const int M = B_ * T_;                                   // 131072 rows
    const size_t gx_f32 = (size_t)M * G3_ * sizeof(float);   // 201.3 MB

    float* gx = (float*)d_ws;
    float* h1 = (float*)((char*)d_ws + gx_f32);              // 67.1 MB

    dim3 ggx(G3_ / TN, M / TM);   // (3, 1024)
    dim3 bgx(256);
    dim3 grec(B_), brec(1024);

    hipLaunchKernelGGL((gx_gemm<true>), ggx, bgx, 0, stream,
                       nullptr, x, emb, W_ih, b_ih, gx);
    hipLaunchKernelGGL((gru_rec<true, false>), grec, brec, 0, stream,
                       gx, W_hh, b_hh, h1, nullptr, nullptr, nullptr);
    hipLaunchKernelGGL((gx_gemm<false>), ggx, bgx, 0, stream,
                       h1, nullptr, nullptr, W_ih + G3_ * H_, b_ih + G3_, gx);
    hipLaunchKernelGGL((gru_rec<false, true>), grec, brec, 0, stream,
                       gx, W_hh + G3_ * H_, b_hh + G3_, nullptr, fc_w, fc_b, out);
}

// Round 10
// 1156.994 us; speedup vs baseline: 1.0302x; 1.0302x over previous
//
#include <hip/hip_runtime.h>
#include <hip/hip_bf16.h>

#define B_   256
#define T_   512
#define H_   128
#define G3_  384

// ---- tiled GEMM config ----
#define TM   128
#define TN   128
#define TK   32
#define LDA  132

__device__ __forceinline__ float sigmoid_f(float x) {
    return 1.0f / (1.0f + __expf(-x));
}
__device__ __forceinline__ float tanh_f(float x) {
    return 1.0f - 2.0f / (__expf(2.0f * x) + 1.0f);
}

// Butterfly sum over each aligned 8-lane group, pure DPP, valid on all lanes.
__device__ __forceinline__ float bfly_fold8(float v) {
    int x;
    x = __builtin_amdgcn_update_dpp(0, __float_as_int(v), 0x0B1, 0xF, 0xF, true);
    v += __int_as_float(x);   // xor 1
    x = __builtin_amdgcn_update_dpp(0, __float_as_int(v), 0x04E, 0xF, 0xF, true);
    v += __int_as_float(x);   // xor 2
    x = __builtin_amdgcn_update_dpp(0, __float_as_int(v), 0x141, 0xF, 0xF, true);
    v += __int_as_float(x);   // half mirror (other quad)
    return v;
}

#define DOT4(acc, hv, wv)                                        \
    acc = fmaf((hv).x, (wv).x, acc);                             \
    acc = fmaf((hv).y, (wv).y, acc);                             \
    acc = fmaf((hv).z, (wv).z, acc);                             \
    acc = fmaf((hv).w, (wv).w, acc);

// volatile 4-float load: cannot be rematerialized -> the values must either
// stay in registers or be honestly spilled (never silently re-loaded in-loop)
#define VLD4(dst, base, off) {                                   \
    const volatile float* _p = (base) + (off);                   \
    dst.x = _p[0]; dst.y = _p[1]; dst.z = _p[2]; dst.w = _p[3]; }

#define WROW_DECL(r) float4 w##r##_0, w##r##_1, w##r##_2, w##r##_3;
#define WROW_LOAD(r) {                                           \
    const float* _wr = Whh + (size_t)(j0 + r) * H_ + ks * 16;    \
    VLD4(w##r##_0, _wr, 0)  VLD4(w##r##_1, _wr, 4)               \
    VLD4(w##r##_2, _wr, 8)  VLD4(w##r##_3, _wr, 12) }
#define WROW_DOT(r, p)                                           \
    DOT4(p, hv0, w##r##_0) DOT4(p, hv1, w##r##_1)                \
    DOT4(p, hv2, w##r##_2) DOT4(p, hv3, w##r##_3)

// ---------------------------------------------------------------------------
// gx GEMM (unchanged from R2 — healthy)
// ---------------------------------------------------------------------------
template<bool GATHER>
__global__ __launch_bounds__(256, 2)
void gx_gemm(const float* __restrict__ X,
             const int*   __restrict__ idx,
             const float* __restrict__ emb,
             const float* __restrict__ W,     // [384,128] row-major
             const float* __restrict__ bias,  // [384]
             float*       __restrict__ gx)    // [M,384]
{
    __shared__ __align__(16) float As[2][TK][LDA];
    __shared__ __align__(16) float Bs[2][TK][LDA];

    const int tid = threadIdx.x;
    const int tn  = tid & 15;
    const int tm  = tid >> 4;
    const int n0  = blockIdx.x * TN;
    const int m0  = blockIdx.y * TM;

    const int q  = tid & 7;
    const float* rowA[4];
    const float* rowB[4];
#pragma unroll
    for (int s = 0; s < 4; s++) {
        const int r = (tid >> 3) + 32 * s;
        rowA[s] = GATHER ? (emb + (size_t)idx[m0 + r] * H_)
                         : (X + (size_t)(m0 + r) * H_);
        rowB[s] = W + (size_t)(n0 + r) * H_;
    }

    float4 stA[4], stB[4];
    auto load_chunk = [&](int kc) {
#pragma unroll
        for (int s = 0; s < 4; s++) {
            stA[s] = *(const float4*)(rowA[s] + kc + q * 4);
            stB[s] = *(const float4*)(rowB[s] + kc + q * 4);
        }
    };
    auto store_chunk = [&](int buf) {
#pragma unroll
        for (int s = 0; s < 4; s++) {
            const int r = (tid >> 3) + 32 * s;
#pragma unroll
            for (int d = 0; d < 4; d++) {
                As[buf][q * 4 + d][r] = ((const float*)&stA[s])[d];
                Bs[buf][q * 4 + d][r] = ((const float*)&stB[s])[d];
            }
        }
    };

    float4 acc[2][2][4];
#pragma unroll
    for (int a = 0; a < 2; a++)
#pragma unroll
        for (int b = 0; b < 2; b++)
#pragma unroll
            for (int c = 0; c < 4; c++) acc[a][b][c] = make_float4(0.f, 0.f, 0.f, 0.f);

    load_chunk(0);
    store_chunk(0);
    __syncthreads();

    for (int c = 0; c < 4; c++) {
        if (c < 3) load_chunk((c + 1) * TK);
        const int buf = c & 1;
#pragma unroll 4
        for (int k = 0; k < TK; k++) {
            float4 a0 = *(const float4*)&As[buf][k][tm * 4];
            float4 a1 = *(const float4*)&As[buf][k][64 + tm * 4];
            float4 b0 = *(const float4*)&Bs[buf][k][tn * 4];
            float4 b1 = *(const float4*)&Bs[buf][k][64 + tn * 4];
            float4 av[2] = {a0, a1}, bv[2] = {b0, b1};
#pragma unroll
            for (int mg = 0; mg < 2; mg++)
#pragma unroll
                for (int mi = 0; mi < 4; mi++) {
                    const float am = ((const float*)&av[mg])[mi];
#pragma unroll
                    for (int ng = 0; ng < 2; ng++) {
                        acc[mg][ng][mi].x = fmaf(am, bv[ng].x, acc[mg][ng][mi].x);
                        acc[mg][ng][mi].y = fmaf(am, bv[ng].y, acc[mg][ng][mi].y);
                        acc[mg][ng][mi].z = fmaf(am, bv[ng].z, acc[mg][ng][mi].z);
                        acc[mg][ng][mi].w = fmaf(am, bv[ng].w, acc[mg][ng][mi].w);
                    }
                }
        }
        if (c < 3) {
            store_chunk(buf ^ 1);
            __syncthreads();
        }
    }

    const float4 bb0 = *(const float4*)(bias + n0 + tn * 4);
    const float4 bb1 = *(const float4*)(bias + n0 + 64 + tn * 4);
#pragma unroll
    for (int mg = 0; mg < 2; mg++)
#pragma unroll
        for (int mi = 0; mi < 4; mi++) {
            const int m = m0 + mg * 64 + tm * 4 + mi;
            float* dst = gx + (size_t)m * G3_ + n0;
            float4 v0 = acc[mg][0][mi];
            v0.x += bb0.x; v0.y += bb0.y; v0.z += bb0.z; v0.w += bb0.w;
            float4 v1 = acc[mg][1][mi];
            v1.x += bb1.x; v1.y += bb1.y; v1.z += bb1.z; v1.w += bb1.w;
            *(float4*)(dst + tn * 4) = v0;
            *(float4*)(dst + 64 + tn * 4) = v1;
        }
}

// ---------------------------------------------------------------------------
// GRU recurrence R10: 256 threads (4 waves) per block, one block per batch
// row (grid=256 -> exactly 1 block/CU -> 4 waves on 4 SIMDs = 1 wave/EU, so
// amdgpu_waves_per_eu(1,1) is the literal truth -> register budget 512).
// De-templated (runtime uniform flags) in case hipcc drops AMDGPU attributes
// on template instantiations (suspected from R4/R5/R9 failures).
//
// Thread (jg = tid>>3, ks = tid&7): owns W_hh rows 12jg..12jg+11, cols
// ks*16..+15 = 192 floats in 48 named volatile-loaded float4s.
// Per step: 4 ds_read_b128 of swizzled h (8 distinct addrs covering 32
// banks, 8-lane broadcast each), 192 FMA in 12 independent chains,
// 12 DPP folds, ks==0 lanes write gh via 3 coalesced b128.
// Total LDS/step: 16 reads + ~8 writes — no longer the bottleneck.
//
// h2 swizzle: h[k] at word ((k>>2)&3)*32 + (k>>4)*4 + (k&3)
//   -> read i at words 32i+4ks+{0..3} gives k = 16ks + 4i + c  (verified R7).
// ---------------------------------------------------------------------------
__attribute__((amdgpu_flat_work_group_size(256, 256), amdgpu_waves_per_eu(1, 1)))
__global__ void gru_rec(const float* __restrict__ gx,   // [B,T,384]
                        const float* __restrict__ Whh,  // [384,128]
                        const float* __restrict__ bhh,  // [384]
                        float*       __restrict__ hseq, // [B,T,128] if store_h
                        const float* __restrict__ fc_w, // [3,128]  if is_final
                        const float* __restrict__ fc_b, // [3]      if is_final
                        float*       __restrict__ out,  // [B,3]    if is_final
                        int store_h, int is_final)
{
    __shared__ __align__(16) float h2[H_];   // swizzled h
    __shared__ __align__(16) float gh[G3_];

    const int tid = threadIdx.x;
    const int b   = blockIdx.x;
    const int jg  = tid >> 3;      // 0..31
    const int ks  = tid & 7;       // 0..7
    const int j0  = jg * 12;

    // --- W_hh fragment: 48 float4 (192 VGPRs), volatile-loaded ---
    WROW_DECL(0)  WROW_DECL(1)  WROW_DECL(2)  WROW_DECL(3)
    WROW_DECL(4)  WROW_DECL(5)  WROW_DECL(6)  WROW_DECL(7)
    WROW_DECL(8)  WROW_DECL(9)  WROW_DECL(10) WROW_DECL(11)
    WROW_LOAD(0)  WROW_LOAD(1)  WROW_LOAD(2)  WROW_LOAD(3)
    WROW_LOAD(4)  WROW_LOAD(5)  WROW_LOAD(6)  WROW_LOAD(7)
    WROW_LOAD(8)  WROW_LOAD(9)  WROW_LOAD(10) WROW_LOAD(11)

    // --- gate-thread state (tid < 128) ---
    const bool gate = (tid < H_);
    float bhr = 0.f, bhz = 0.f, bhn = 0.f;
    float gr = 0.f, gz = 0.f, gn = 0.f;
    float h_old = 0.f;
    int   hw = 0;
    const float* gxb = gx + (size_t)b * T_ * G3_;
    if (gate) {
        bhr = bhh[tid]; bhz = bhh[tid + H_]; bhn = bhh[tid + 2 * H_];
        gr = gxb[tid]; gz = gxb[tid + H_]; gn = gxb[tid + 2 * H_];
        hw = ((tid >> 2) & 3) * 32 + (tid >> 4) * 4 + (tid & 3);
        h2[tid] = 0.0f;   // zeros are swizzle-invariant
    }
    __syncthreads();

    const int hb = ks * 4;  // base word of this thread's k-slice (swizzled)

    for (int t = 0; t < T_; t++) {
        // prefetch next step's gx (covered by this step's compute)
        float gr2 = 0.f, gz2 = 0.f, gn2 = 0.f;
        if (gate) {
            const float* gnx = gxb + (size_t)min(t + 1, T_ - 1) * G3_;
            gr2 = gnx[tid]; gz2 = gnx[tid + H_]; gn2 = gnx[tid + 2 * H_];
        }

        // ---- phase A: 12 partial dots over this thread's k-slice ----
        const float4 hv0 = *(const float4*)&h2[hb];
        const float4 hv1 = *(const float4*)&h2[32 + hb];
        const float4 hv2 = *(const float4*)&h2[64 + hb];
        const float4 hv3 = *(const float4*)&h2[96 + hb];

        float p0 = 0.f, p1 = 0.f, p2 = 0.f, p3 = 0.f, p4 = 0.f, p5 = 0.f;
        float p6 = 0.f, p7 = 0.f, p8 = 0.f, p9 = 0.f, p10 = 0.f, p11 = 0.f;
        WROW_DOT(0, p0)   WROW_DOT(1, p1)   WROW_DOT(2, p2)
        WROW_DOT(3, p3)   WROW_DOT(4, p4)   WROW_DOT(5, p5)
        WROW_DOT(6, p6)   WROW_DOT(7, p7)   WROW_DOT(8, p8)
        WROW_DOT(9, p9)   WROW_DOT(10, p10) WROW_DOT(11, p11)

        p0 = bfly_fold8(p0);   p1 = bfly_fold8(p1);   p2 = bfly_fold8(p2);
        p3 = bfly_fold8(p3);   p4 = bfly_fold8(p4);   p5 = bfly_fold8(p5);
        p6 = bfly_fold8(p6);   p7 = bfly_fold8(p7);   p8 = bfly_fold8(p8);
        p9 = bfly_fold8(p9);   p10 = bfly_fold8(p10); p11 = bfly_fold8(p11);

        if (ks == 0) {   // 12 contiguous outputs -> 3 coalesced b128 stores
            *(float4*)&gh[j0]     = make_float4(p0, p1, p2, p3);
            *(float4*)&gh[j0 + 4] = make_float4(p4, p5, p6, p7);
            *(float4*)&gh[j0 + 8] = make_float4(p8, p9, p10, p11);
        }
        __syncthreads();

        // ---- phase B: gates on threads 0..127 ----
        if (gate) {
            const float ghr = gh[tid] + bhr;
            const float ghz = gh[tid + H_] + bhz;
            const float ghn = gh[tid + 2 * H_] + bhn;
            const float r = sigmoid_f(gr + ghr);
            const float z = sigmoid_f(gz + ghz);
            const float n = tanh_f(gn + r * ghn);
            h_old = (1.0f - z) * n + z * h_old;
            h2[hw] = h_old;
            if (store_h) hseq[((size_t)b * T_ + t) * H_ + tid] = h_old;
            gr = gr2; gz = gz2; gn = gn2;
        }
        __syncthreads();
    }

    if (is_final) {
        if (gate) gh[tid] = fmaxf(h_old, 0.0f);   // relu(last hidden)
        __syncthreads();
        if (tid < 3) {
            float acc = fc_b[tid];
            const float* fw = fc_w + tid * H_;
#pragma unroll
            for (int k = 0; k < H_; k++) acc = fmaf(gh[k], fw[k], acc);
            out[b * 3 + tid] = acc;
        }
    }
}

// ---------------------------------------------------------------------------
extern "C" void kernel_launch(void* const* d_in, const int* in_sizes, int n_in,
                              void* d_out, int out_size, void* d_ws, size_t ws_size,
                              hipStream_t stream)
{
    const int*   x    = (const int*)  d_in[0];
    const float* emb  = (const float*)d_in[1];
    const float* W_ih = (const float*)d_in[2];  // [2,384,128]
    const float* W_hh = (const float*)d_in[3];  // [2,384,128]
    const float* b_ih = (const float*)d_in[4];  // [2,384]
    const float* b_hh = (const float*)d_in[5];  // [2,384]
    const float* fc_w = (const float*)d_in[6];  // [3,128]
    const float* fc_b = (const float*)d_in[7];  // [3]
    float* out = (float*)d_out;

    const int M = B_ * T_;                                   // 131072 rows
    const size_t gx_f32 = (size_t)M * G3_ * sizeof(float);   // 201.3 MB

    float* gx = (float*)d_ws;
    float* h1 = (float*)((char*)d_ws + gx_f32);              // 67.1 MB

    dim3 ggx(G3_ / TN, M / TM);   // (3, 1024)
    dim3 bgx(256);
    dim3 grec(B_), brec(256);

    hipLaunchKernelGGL((gx_gemm<true>), ggx, bgx, 0, stream,
                       nullptr, x, emb, W_ih, b_ih, gx);
    hipLaunchKernelGGL(gru_rec, grec, brec, 0, stream,
                       gx, W_hh, b_hh, h1, nullptr, nullptr, nullptr, 1, 0);
    hipLaunchKernelGGL((gx_gemm<false>), ggx, bgx, 0, stream,
                       h1, nullptr, nullptr, W_ih + G3_ * H_, b_ih + G3_, gx);
    hipLaunchKernelGGL(gru_rec, grec, brec, 0, stream,
                       gx, W_hh + G3_ * H_, b_hh + G3_, nullptr, fc_w, fc_b, out, 0, 1);
}